// Round 1
// baseline (3468.950 us; speedup 1.0000x reference)
//
#include <hip/hip_runtime.h>
#include <math.h>

#define NN 50000      // nodes
#define NG 500        // graphs
#define DD 64
#define HH 128
#define CC 10

static inline int cdiv(int a, int b) { return (a + b - 1) / b; }

// ---------------- degree / dinv ----------------
__global__ void init_deg_kernel(float* __restrict__ deg) {
    int n = blockIdx.x * 256 + threadIdx.x;
    if (n < NN) deg[n] = 1.0f;  // self-loop
}

__global__ void deg_edges_kernel(const int* __restrict__ dst, float* __restrict__ deg, int nedges) {
    int e = blockIdx.x * 256 + threadIdx.x;
    if (e < nedges) atomicAdd(&deg[dst[e]], 1.0f);
}

__global__ void dinv_kernel(const float* __restrict__ deg, float* __restrict__ dinv) {
    int n = blockIdx.x * 256 + threadIdx.x;
    if (n < NN) dinv[n] = 1.0f / sqrtf(deg[n]);  // deg >= 1 always (self-loop)
}

// ---------------- MLP embedder: relu(relu(x W1 + b1) W2 + b2) ----------------
__global__ __launch_bounds__(256) void embed_kernel(
    const float* __restrict__ x,
    const float* __restrict__ w1, const float* __restrict__ b1,
    const float* __restrict__ w2, const float* __restrict__ b2,
    float* __restrict__ out)  // [NN,64] stride 64
{
    __shared__ float sW1[64 * 64];
    __shared__ float sW2[64 * 64];
    __shared__ float sB1[64], sB2[64];
    __shared__ float sX[16][64];
    __shared__ float sH[16][64];
    int tid = threadIdx.x;
    for (int i = tid; i < 64 * 64; i += 256) { sW1[i] = w1[i]; sW2[i] = w2[i]; }
    if (tid < 64) { sB1[tid] = b1[tid]; sB2[tid] = b2[tid]; }
    int base = blockIdx.x * 16;
    for (int i = tid; i < 16 * 64; i += 256) {
        int n = i >> 6, k = i & 63;
        int gn = base + n;
        sX[n][k] = (gn < NN) ? x[gn * 64 + k] : 0.0f;
    }
    __syncthreads();
    int o = tid & 63;
    int nsub = tid >> 6;  // 0..3
    for (int p = 0; p < 4; ++p) {
        int n = p * 4 + nsub;
        float acc = sB1[o];
        #pragma unroll 8
        for (int k = 0; k < 64; ++k) acc += sX[n][k] * sW1[k * 64 + o];
        sH[n][o] = fmaxf(acc, 0.0f);
    }
    __syncthreads();
    for (int p = 0; p < 4; ++p) {
        int n = p * 4 + nsub;
        int gn = base + n;
        if (gn >= NN) continue;
        float acc = sB2[o];
        #pragma unroll 8
        for (int k = 0; k < 64; ++k) acc += sH[n][k] * sW2[k * 64 + o];
        out[gn * 64 + o] = fmaxf(acc, 0.0f);
    }
}

// ---------------- generic node-feature matmul: out = (relu?)h @ W ----------------
template <int IN, int OUT, int NB, bool RELU_IN>
__global__ __launch_bounds__(256) void gcn_matmul_kernel(
    const float* __restrict__ h, int hstride,
    const float* __restrict__ w,
    float* __restrict__ out, int ostride)
{
    __shared__ float sW[IN * OUT];
    __shared__ float sX[NB][IN];
    int tid = threadIdx.x;
    for (int i = tid; i < IN * OUT; i += 256) sW[i] = w[i];
    int base = blockIdx.x * NB;
    for (int i = tid; i < NB * IN; i += 256) {
        int n = i / IN, k = i % IN;
        int gn = base + n;
        float v = (gn < NN) ? h[gn * hstride + k] : 0.0f;
        sX[n][k] = RELU_IN ? fmaxf(v, 0.0f) : v;
    }
    __syncthreads();
    for (int idx = tid; idx < NB * OUT; idx += 256) {
        int n = idx / OUT, o = idx % OUT;
        int gn = base + n;
        if (gn >= NN) continue;
        float acc = 0.0f;
        #pragma unroll 8
        for (int k = 0; k < IN; ++k) acc += sX[n][k] * sW[k * OUT + o];
        out[gn * ostride + o] = acc;
    }
}

// ---------------- init: out[n][c] = b[c] + hw[n][c]*dinv[n]^2 (self-loop term) ----------------
template <int OUT, int OSTRIDE>
__global__ void gcn_init_kernel(const float* __restrict__ hw, const float* __restrict__ b,
                                const float* __restrict__ dinv, float* __restrict__ out)
{
    long long idx = (long long)blockIdx.x * 256 + threadIdx.x;
    if (idx >= (long long)NN * OUT) return;
    int n = (int)(idx / OUT), c = (int)(idx % OUT);
    float di = dinv[n];
    out[n * OSTRIDE + c] = b[c] + hw[n * OSTRIDE + c] * di * di;
}

// ---------------- edge scatter (OUT=128): out[dst] += hw[src]*norm ----------------
__global__ void gcn_scatter128_kernel(const int* __restrict__ src, const int* __restrict__ dst,
                                      const float* __restrict__ dinv, const float* __restrict__ hw,
                                      float* __restrict__ out, int nedges)
{
    int t = blockIdx.x * 256 + threadIdx.x;
    int e = t >> 5;  // 32 threads/edge, 4 channels each
    if (e >= nedges) return;
    int c = (t & 31) * 4;
    int s = src[e], d = dst[e];
    float norm = dinv[s] * dinv[d];
    const float4 v = *reinterpret_cast<const float4*>(hw + (long long)s * 128 + c);
    atomicAdd(&out[(long long)d * 128 + c + 0], v.x * norm);
    atomicAdd(&out[(long long)d * 128 + c + 1], v.y * norm);
    atomicAdd(&out[(long long)d * 128 + c + 2], v.z * norm);
    atomicAdd(&out[(long long)d * 128 + c + 3], v.w * norm);
}

// ---------------- edge scatter (OUT=10, stride 16) ----------------
__global__ void gcn_scatter10_kernel(const int* __restrict__ src, const int* __restrict__ dst,
                                     const float* __restrict__ dinv, const float* __restrict__ hw,
                                     float* __restrict__ out, int nedges)
{
    int e = blockIdx.x * 256 + threadIdx.x;
    if (e >= nedges) return;
    int s = src[e], d = dst[e];
    float norm = dinv[s] * dinv[d];
    #pragma unroll
    for (int c = 0; c < 10; ++c) atomicAdd(&out[d * 16 + c], hw[s * 16 + c] * norm);
}

// ---------------- pooling ----------------
__global__ void zero_pool_kernel(float* __restrict__ pooled, float* __restrict__ cnt) {
    int i = blockIdx.x * 256 + threadIdx.x;
    if (i < NG * CC) pooled[i] = 0.0f;
    if (i < NG) cnt[i] = 0.0f;
}

__global__ void pool_kernel(const float* __restrict__ h3, const int* __restrict__ batch,
                            float* __restrict__ pooled, float* __restrict__ cnt)
{
    int n = blockIdx.x * 256 + threadIdx.x;
    if (n >= NN) return;
    int g = batch[n];
    #pragma unroll
    for (int c = 0; c < 10; ++c) atomicAdd(&pooled[g * 10 + c], h3[n * 16 + c]);
    atomicAdd(&cnt[g], 1.0f);
}

__global__ void pool_finish_kernel(const float* __restrict__ pooled, const float* __restrict__ cnt,
                                   float* __restrict__ out)
{
    int g = blockIdx.x * 64 + threadIdx.x;
    if (g >= NG) return;
    float c = fmaxf(cnt[g], 1.0f);
    float v[10];
    float m = -1e30f;
    #pragma unroll
    for (int i = 0; i < 10; ++i) { v[i] = pooled[g * 10 + i] / c; m = fmaxf(m, v[i]); }
    float s = 0.0f;
    #pragma unroll
    for (int i = 0; i < 10; ++i) s += expf(v[i] - m);
    float lse = m + logf(s);
    #pragma unroll
    for (int i = 0; i < 10; ++i) out[g * 10 + i] = v[i] - lse;
}

extern "C" void kernel_launch(void* const* d_in, const int* in_sizes, int n_in,
                              void* d_out, int out_size, void* d_ws, size_t ws_size,
                              hipStream_t stream)
{
    const float* x      = (const float*)d_in[0];
    const int*   ei     = (const int*)d_in[1];
    const int*   batch  = (const int*)d_in[2];
    const float* emb_w1 = (const float*)d_in[3];
    const float* emb_b1 = (const float*)d_in[4];
    const float* emb_w2 = (const float*)d_in[5];
    const float* emb_b2 = (const float*)d_in[6];
    const float* w1     = (const float*)d_in[7];
    const float* b1     = (const float*)d_in[8];
    const float* w2     = (const float*)d_in[9];
    const float* b2     = (const float*)d_in[10];
    const float* w3     = (const float*)d_in[11];
    const float* b3     = (const float*)d_in[12];

    int E = in_sizes[1] / 2;
    const int* src = ei;
    const int* dst = ei + E;

    // workspace layout
    char* ws = (char*)d_ws;
    float* bufA   = (float*)(ws);                               // NN*128 f32 = 25.6 MB
    float* bufB   = (float*)(ws + (size_t)NN * 128 * 4);        // NN*128 f32 = 25.6 MB
    float* deg    = (float*)(ws + (size_t)NN * 128 * 4 * 2);    // NN f32
    float* dinv   = deg + NN;                                   // NN f32
    float* pooled = dinv + NN;                                  // NG*CC f32
    float* cnt    = pooled + NG * CC;                           // NG f32

    // structure
    init_deg_kernel<<<cdiv(NN, 256), 256, 0, stream>>>(deg);
    deg_edges_kernel<<<cdiv(E, 256), 256, 0, stream>>>(dst, deg, E);
    dinv_kernel<<<cdiv(NN, 256), 256, 0, stream>>>(deg, dinv);

    // embedder -> bufA [NN,64]
    embed_kernel<<<cdiv(NN, 16), 256, 0, stream>>>(x, emb_w1, emb_b1, emb_w2, emb_b2, bufA);

    // GCN layer 1: 64 -> 128
    gcn_matmul_kernel<64, 128, 8, false><<<cdiv(NN, 8), 256, 0, stream>>>(bufA, 64, w1, bufB, 128);
    gcn_init_kernel<128, 128><<<cdiv(NN * 128, 256), 256, 0, stream>>>(bufB, b1, dinv, bufA);
    gcn_scatter128_kernel<<<cdiv(E * 32, 256), 256, 0, stream>>>(src, dst, dinv, bufB, bufA, E);

    // GCN layer 2: 128 -> 128 (relu on input)
    gcn_matmul_kernel<128, 128, 8, true><<<cdiv(NN, 8), 256, 0, stream>>>(bufA, 128, w2, bufB, 128);
    gcn_init_kernel<128, 128><<<cdiv(NN * 128, 256), 256, 0, stream>>>(bufB, b2, dinv, bufA);
    gcn_scatter128_kernel<<<cdiv(E * 32, 256), 256, 0, stream>>>(src, dst, dinv, bufB, bufA, E);

    // GCN layer 3: 128 -> 10 (relu on input), stride-16 rows
    gcn_matmul_kernel<128, 10, 16, true><<<cdiv(NN, 16), 256, 0, stream>>>(bufA, 128, w3, bufB, 16);
    gcn_init_kernel<10, 16><<<cdiv(NN * 10, 256), 256, 0, stream>>>(bufB, b3, dinv, bufA);
    gcn_scatter10_kernel<<<cdiv(E, 256), 256, 0, stream>>>(src, dst, dinv, bufB, bufA, E);

    // pooling + log_softmax
    zero_pool_kernel<<<cdiv(NG * CC, 256), 256, 0, stream>>>(pooled, cnt);
    pool_kernel<<<cdiv(NN, 256), 256, 0, stream>>>(bufA, batch, pooled, cnt);
    pool_finish_kernel<<<cdiv(NG, 64), 64, 0, stream>>>(pooled, cnt, (float*)d_out);
}

// Round 2
// 534.163 us; speedup vs baseline: 6.4942x; 6.4942x over previous
//
#include <hip/hip_runtime.h>
#include <math.h>

#define NN 50000      // nodes
#define NG 500        // graphs
#define DD 64
#define HH 128
#define CC 10
#define NBS 196       // cdiv(NN,256) scan blocks

static inline int cdiv(int a, int b) { return (a + b - 1) / b; }

// ---------------- CSR build ----------------
__global__ void zero_int_kernel(int* __restrict__ a, int* __restrict__ b) {
    int i = blockIdx.x * 256 + threadIdx.x;
    if (i < NN) { a[i] = 0; b[i] = 0; }
}

__global__ void count_kernel(const int* __restrict__ dst, int* __restrict__ cnt, int nedges) {
    int e = blockIdx.x * 256 + threadIdx.x;
    if (e < nedges) atomicAdd(&cnt[dst[e]], 1);
}

__global__ void dinv_kernel(const int* __restrict__ cnt, float* __restrict__ dinv) {
    int n = blockIdx.x * 256 + threadIdx.x;
    if (n < NN) dinv[n] = rsqrtf((float)cnt[n] + 1.0f);  // +1 self-loop
}

// exclusive scan of cnt -> ptr (3 kernels)
__global__ void scan_block_kernel(const int* __restrict__ cnt, int* __restrict__ ptr, int* __restrict__ bsum) {
    __shared__ int s[256];
    int b = blockIdx.x, t = threadIdx.x;
    int i = b * 256 + t;
    int v = (i < NN) ? cnt[i] : 0;
    s[t] = v; __syncthreads();
    for (int off = 1; off < 256; off <<= 1) {
        int x = (t >= off) ? s[t - off] : 0; __syncthreads();
        s[t] += x; __syncthreads();
    }
    if (i < NN) ptr[i] = s[t] - v;
    if (t == 255) bsum[b] = s[255];
}

__global__ void scan_tops_kernel(int* __restrict__ bsum) {
    __shared__ int s[256];
    int t = threadIdx.x;
    int v = (t < NBS) ? bsum[t] : 0;
    s[t] = v; __syncthreads();
    for (int off = 1; off < 256; off <<= 1) {
        int x = (t >= off) ? s[t - off] : 0; __syncthreads();
        s[t] += x; __syncthreads();
    }
    if (t < NBS) bsum[t] = s[t] - v;
}

__global__ void scan_add_kernel(int* __restrict__ ptr, const int* __restrict__ bsum) {
    int i = blockIdx.x * 256 + threadIdx.x;
    if (i < NN) ptr[i] += bsum[blockIdx.x];
}

__global__ void csr_fill_kernel(const int* __restrict__ src, const int* __restrict__ dst,
                                const int* __restrict__ ptr, int* __restrict__ fill,
                                int* __restrict__ csr_src, int nedges) {
    int e = blockIdx.x * 256 + threadIdx.x;
    if (e >= nedges) return;
    int d = dst[e];
    int pos = ptr[d] + atomicAdd(&fill[d], 1);
    csr_src[pos] = src[e];
}

// ---------------- MLP embedder: relu(relu(x W1 + b1) W2 + b2) ----------------
__global__ __launch_bounds__(256) void embed_kernel(
    const float* __restrict__ x,
    const float* __restrict__ w1, const float* __restrict__ b1,
    const float* __restrict__ w2, const float* __restrict__ b2,
    float* __restrict__ out)
{
    __shared__ float sW1[64 * 64];
    __shared__ float sW2[64 * 64];
    __shared__ float sB1[64], sB2[64];
    __shared__ float sX[16][64];
    __shared__ float sH[16][64];
    int tid = threadIdx.x;
    for (int i = tid; i < 64 * 64; i += 256) { sW1[i] = w1[i]; sW2[i] = w2[i]; }
    if (tid < 64) { sB1[tid] = b1[tid]; sB2[tid] = b2[tid]; }
    int base = blockIdx.x * 16;
    for (int i = tid; i < 16 * 64; i += 256) {
        int n = i >> 6, k = i & 63;
        int gn = base + n;
        sX[n][k] = (gn < NN) ? x[gn * 64 + k] : 0.0f;
    }
    __syncthreads();
    int o = tid & 63;
    int nsub = tid >> 6;
    for (int p = 0; p < 4; ++p) {
        int n = p * 4 + nsub;
        float acc = sB1[o];
        #pragma unroll 8
        for (int k = 0; k < 64; ++k) acc += sX[n][k] * sW1[k * 64 + o];
        sH[n][o] = fmaxf(acc, 0.0f);
    }
    __syncthreads();
    for (int p = 0; p < 4; ++p) {
        int n = p * 4 + nsub;
        int gn = base + n;
        if (gn >= NN) continue;
        float acc = sB2[o];
        #pragma unroll 8
        for (int k = 0; k < 64; ++k) acc += sH[n][k] * sW2[k * 64 + o];
        out[gn * 64 + o] = fmaxf(acc, 0.0f);
    }
}

// ---------------- generic node-feature matmul: out = (relu?)h @ W ----------------
template <int IN, int OUT, int NB, bool RELU_IN>
__global__ __launch_bounds__(256) void gcn_matmul_kernel(
    const float* __restrict__ h, int hstride,
    const float* __restrict__ w,
    float* __restrict__ out, int ostride)
{
    __shared__ float sW[IN * OUT];
    __shared__ float sX[NB][IN];
    int tid = threadIdx.x;
    for (int i = tid; i < IN * OUT; i += 256) sW[i] = w[i];
    int base = blockIdx.x * NB;
    for (int i = tid; i < NB * IN; i += 256) {
        int n = i / IN, k = i % IN;
        int gn = base + n;
        float v = (gn < NN) ? h[gn * hstride + k] : 0.0f;
        sX[n][k] = RELU_IN ? fmaxf(v, 0.0f) : v;
    }
    __syncthreads();
    for (int idx = tid; idx < NB * OUT; idx += 256) {
        int n = idx / OUT, o = idx % OUT;
        int gn = base + n;
        if (gn >= NN) continue;
        float acc = 0.0f;
        #pragma unroll 8
        for (int k = 0; k < IN; ++k) acc += sX[n][k] * sW[k * OUT + o];
        out[gn * ostride + o] = acc;
    }
}

// ---------------- CSR gather, 128 channels: one wave per node ----------------
__global__ __launch_bounds__(256) void gcn_gather128_kernel(
    const int* __restrict__ csr_src, const int* __restrict__ ptr, const int* __restrict__ cnt,
    const float* __restrict__ dinv, const float* __restrict__ hw, const float* __restrict__ b,
    float* __restrict__ out)
{
    int tid = threadIdx.x;
    int n = blockIdx.x * 4 + (tid >> 6);
    if (n >= NN) return;
    int lane = tid & 63;
    float di = dinv[n];
    float2 h0 = *reinterpret_cast<const float2*>(hw + (size_t)n * 128 + lane * 2);
    float2 bb = *reinterpret_cast<const float2*>(b + lane * 2);
    float ax = bb.x + h0.x * di * di;
    float ay = bb.y + h0.y * di * di;
    int s0 = ptr[n], c = cnt[n];
    int i = 0;
    for (; i + 1 < c; i += 2) {
        int sa = csr_src[s0 + i];
        int sb = csr_src[s0 + i + 1];
        float na = dinv[sa] * di;
        float nb = dinv[sb] * di;
        float2 va = *reinterpret_cast<const float2*>(hw + (size_t)sa * 128 + lane * 2);
        float2 vb = *reinterpret_cast<const float2*>(hw + (size_t)sb * 128 + lane * 2);
        ax += va.x * na + vb.x * nb;
        ay += va.y * na + vb.y * nb;
    }
    if (i < c) {
        int sa = csr_src[s0 + i];
        float na = dinv[sa] * di;
        float2 va = *reinterpret_cast<const float2*>(hw + (size_t)sa * 128 + lane * 2);
        ax += va.x * na;
        ay += va.y * na;
    }
    float2 r; r.x = ax; r.y = ay;
    *reinterpret_cast<float2*>(out + (size_t)n * 128 + lane * 2) = r;
}

// ---------------- CSR gather, 10 channels (stride 16): 16 threads per node ----------------
__global__ __launch_bounds__(256) void gcn_gather10_kernel(
    const int* __restrict__ csr_src, const int* __restrict__ ptr, const int* __restrict__ cnt,
    const float* __restrict__ dinv, const float* __restrict__ hw, const float* __restrict__ b,
    float* __restrict__ out)
{
    int idx = blockIdx.x * 256 + threadIdx.x;
    int n = idx >> 4;
    int ch = idx & 15;
    if (n >= NN || ch >= 10) return;
    float di = dinv[n];
    float acc = b[ch] + hw[n * 16 + ch] * di * di;
    int s0 = ptr[n], c = cnt[n];
    for (int i = 0; i < c; ++i) {
        int s = csr_src[s0 + i];
        acc += hw[s * 16 + ch] * (dinv[s] * di);
    }
    out[n * 16 + ch] = acc;
}

// ---------------- pooling ----------------
__global__ void zero_pool_kernel(float* __restrict__ pooled, float* __restrict__ pcnt) {
    int i = blockIdx.x * 256 + threadIdx.x;
    if (i < NG * CC) pooled[i] = 0.0f;
    if (i < NG) pcnt[i] = 0.0f;
}

__global__ void pool_kernel(const float* __restrict__ h3, const int* __restrict__ batch,
                            float* __restrict__ pooled, float* __restrict__ pcnt)
{
    int n = blockIdx.x * 256 + threadIdx.x;
    if (n >= NN) return;
    int g = batch[n];
    #pragma unroll
    for (int c = 0; c < 10; ++c) atomicAdd(&pooled[g * 10 + c], h3[n * 16 + c]);
    atomicAdd(&pcnt[g], 1.0f);
}

__global__ void pool_finish_kernel(const float* __restrict__ pooled, const float* __restrict__ pcnt,
                                   float* __restrict__ out)
{
    int g = blockIdx.x * 64 + threadIdx.x;
    if (g >= NG) return;
    float c = fmaxf(pcnt[g], 1.0f);
    float v[10];
    float m = -1e30f;
    #pragma unroll
    for (int i = 0; i < 10; ++i) { v[i] = pooled[g * 10 + i] / c; m = fmaxf(m, v[i]); }
    float s = 0.0f;
    #pragma unroll
    for (int i = 0; i < 10; ++i) s += expf(v[i] - m);
    float lse = m + logf(s);
    #pragma unroll
    for (int i = 0; i < 10; ++i) out[g * 10 + i] = v[i] - lse;
}

extern "C" void kernel_launch(void* const* d_in, const int* in_sizes, int n_in,
                              void* d_out, int out_size, void* d_ws, size_t ws_size,
                              hipStream_t stream)
{
    const float* x      = (const float*)d_in[0];
    const int*   ei     = (const int*)d_in[1];
    const int*   batch  = (const int*)d_in[2];
    const float* emb_w1 = (const float*)d_in[3];
    const float* emb_b1 = (const float*)d_in[4];
    const float* emb_w2 = (const float*)d_in[5];
    const float* emb_b2 = (const float*)d_in[6];
    const float* w1     = (const float*)d_in[7];
    const float* b1     = (const float*)d_in[8];
    const float* w2     = (const float*)d_in[9];
    const float* b2     = (const float*)d_in[10];
    const float* w3     = (const float*)d_in[11];
    const float* b3     = (const float*)d_in[12];

    int E = in_sizes[1] / 2;
    const int* src = ei;
    const int* dst = ei + E;

    // workspace layout
    char* ws = (char*)d_ws;
    size_t off = 0;
    float* bufA   = (float*)(ws + off); off += (size_t)NN * 128 * 4;
    float* bufB   = (float*)(ws + off); off += (size_t)NN * 128 * 4;
    float* dinv   = (float*)(ws + off); off += (size_t)NN * 4;
    int*   cnt    = (int*)(ws + off);   off += (size_t)NN * 4;
    int*   ptr    = (int*)(ws + off);   off += (size_t)NN * 4;
    int*   fill   = (int*)(ws + off);   off += (size_t)NN * 4;
    int*   bsum   = (int*)(ws + off);   off += 256 * 4;
    int*   csrs   = (int*)(ws + off);   off += (size_t)E * 4;
    float* pooled = (float*)(ws + off); off += (size_t)NG * CC * 4;
    float* pcnt   = (float*)(ws + off); off += (size_t)NG * 4;

    // ---- CSR build ----
    zero_int_kernel<<<cdiv(NN, 256), 256, 0, stream>>>(cnt, fill);
    count_kernel<<<cdiv(E, 256), 256, 0, stream>>>(dst, cnt, E);
    dinv_kernel<<<cdiv(NN, 256), 256, 0, stream>>>(cnt, dinv);
    scan_block_kernel<<<NBS, 256, 0, stream>>>(cnt, ptr, bsum);
    scan_tops_kernel<<<1, 256, 0, stream>>>(bsum);
    scan_add_kernel<<<NBS, 256, 0, stream>>>(ptr, bsum);
    csr_fill_kernel<<<cdiv(E, 256), 256, 0, stream>>>(src, dst, ptr, fill, csrs, E);

    // ---- embedder -> bufA [NN,64] ----
    embed_kernel<<<cdiv(NN, 16), 256, 0, stream>>>(x, emb_w1, emb_b1, emb_w2, emb_b2, bufA);

    // ---- GCN layer 1: 64 -> 128 ----
    gcn_matmul_kernel<64, 128, 8, false><<<cdiv(NN, 8), 256, 0, stream>>>(bufA, 64, w1, bufB, 128);
    gcn_gather128_kernel<<<cdiv(NN, 4), 256, 0, stream>>>(csrs, ptr, cnt, dinv, bufB, b1, bufA);

    // ---- GCN layer 2: 128 -> 128 (relu fused into matmul load) ----
    gcn_matmul_kernel<128, 128, 8, true><<<cdiv(NN, 8), 256, 0, stream>>>(bufA, 128, w2, bufB, 128);
    gcn_gather128_kernel<<<cdiv(NN, 4), 256, 0, stream>>>(csrs, ptr, cnt, dinv, bufB, b2, bufA);

    // ---- GCN layer 3: 128 -> 10 (stride-16 rows) ----
    gcn_matmul_kernel<128, 10, 16, true><<<cdiv(NN, 16), 256, 0, stream>>>(bufA, 128, w3, bufB, 16);
    gcn_gather10_kernel<<<cdiv(NN * 16, 256), 256, 0, stream>>>(csrs, ptr, cnt, dinv, bufB, b3, bufA);

    // ---- pooling + log_softmax ----
    zero_pool_kernel<<<cdiv(NG * CC, 256), 256, 0, stream>>>(pooled, pcnt);
    pool_kernel<<<cdiv(NN, 256), 256, 0, stream>>>(bufA, batch, pooled, pcnt);
    pool_finish_kernel<<<cdiv(NG, 64), 64, 0, stream>>>(pooled, pcnt, (float*)d_out);
}

// Round 3
// 404.402 us; speedup vs baseline: 8.5780x; 1.3209x over previous
//
#include <hip/hip_runtime.h>
#include <math.h>

#define NN 50000      // nodes
#define NG 500        // graphs
#define CC 10
#define NBS 196       // cdiv(NN,256) scan blocks

static inline int cdiv(int a, int b) { return (a + b - 1) / b; }

// ---------------- CSR build ----------------
__global__ void zero_int_kernel(int* __restrict__ a, int* __restrict__ b) {
    int i = blockIdx.x * 256 + threadIdx.x;
    if (i < NN) { a[i] = 0; b[i] = 0; }
}

__global__ void count_kernel(const int* __restrict__ dst, int* __restrict__ cnt, int nedges) {
    int e = blockIdx.x * 256 + threadIdx.x;
    if (e < nedges) atomicAdd(&cnt[dst[e]], 1);
}

__global__ void dinv_kernel(const int* __restrict__ cnt, float* __restrict__ dinv) {
    int n = blockIdx.x * 256 + threadIdx.x;
    if (n < NN) dinv[n] = rsqrtf((float)cnt[n] + 1.0f);  // +1 self-loop
}

__global__ void scan_block_kernel(const int* __restrict__ cnt, int* __restrict__ ptr, int* __restrict__ bsum) {
    __shared__ int s[256];
    int b = blockIdx.x, t = threadIdx.x;
    int i = b * 256 + t;
    int v = (i < NN) ? cnt[i] : 0;
    s[t] = v; __syncthreads();
    for (int off = 1; off < 256; off <<= 1) {
        int x = (t >= off) ? s[t - off] : 0; __syncthreads();
        s[t] += x; __syncthreads();
    }
    if (i < NN) ptr[i] = s[t] - v;
    if (t == 255) bsum[b] = s[255];
}

__global__ void scan_tops_kernel(int* __restrict__ bsum) {
    __shared__ int s[256];
    int t = threadIdx.x;
    int v = (t < NBS) ? bsum[t] : 0;
    s[t] = v; __syncthreads();
    for (int off = 1; off < 256; off <<= 1) {
        int x = (t >= off) ? s[t - off] : 0; __syncthreads();
        s[t] += x; __syncthreads();
    }
    if (t < NBS) bsum[t] = s[t] - v;
}

__global__ void scan_add_kernel(int* __restrict__ ptr, const int* __restrict__ bsum) {
    int i = blockIdx.x * 256 + threadIdx.x;
    if (i < NN) ptr[i] += bsum[blockIdx.x];
}

__global__ void csr_fill_kernel(const int* __restrict__ src, const int* __restrict__ dst,
                                const int* __restrict__ ptr, int* __restrict__ fill,
                                int* __restrict__ csr_src, int nedges) {
    int e = blockIdx.x * 256 + threadIdx.x;
    if (e >= nedges) return;
    int d = dst[e];
    int pos = ptr[d] + atomicAdd(&fill[d], 1);
    csr_src[pos] = src[e];
}

// ---------------- register-tiled dense matmul: out = (relu?)(h) @ W [+bias] ----------------
// 64 rows x OUT cols per block; 256 threads; thread tile TM x 4.
template <int K, int OUT, int WCOLS, bool RELU_IN, bool RELU_OUT, bool BIAS>
__global__ __launch_bounds__(256) void mm_kernel(
    const float* __restrict__ h, int hstride,
    const float* __restrict__ w, const float* __restrict__ bias,
    float* __restrict__ out, int ostride)
{
    constexpr int KC = 64;
    constexpr int NCH = K / KC;
    constexpr int NCOL = OUT / 4;       // 32 / 16 / 4
    constexpr int NROW = 256 / NCOL;    // 8 / 16 / 64
    constexpr int TM = 64 / NROW;       // 8 / 4 / 1
    __shared__ float sW[KC * OUT];
    __shared__ float sX[64][KC + 4];    // stride 68: 16B-aligned rows, no 32-way conflicts
    int tid = threadIdx.x;
    int tx = tid % NCOL, ty = tid / NCOL;
    int base = blockIdx.x * 64;
    int r0 = ty * TM;

    float acc[TM][4];
    #pragma unroll
    for (int i = 0; i < TM; ++i) {
        #pragma unroll
        for (int j = 0; j < 4; ++j)
            acc[i][j] = BIAS ? ((tx * 4 + j < WCOLS) ? bias[tx * 4 + j] : 0.0f) : 0.0f;
    }

    for (int ch = 0; ch < NCH; ++ch) {
        int kc = ch * KC;
        if (ch) __syncthreads();  // previous chunk's readers done before overwrite
        if constexpr (WCOLS == OUT) {
            for (int i = tid * 4; i < KC * OUT; i += 1024)
                *reinterpret_cast<float4*>(&sW[i]) =
                    *reinterpret_cast<const float4*>(&w[kc * OUT + i]);
        } else {
            for (int i = tid; i < KC * OUT; i += 256) {
                int k = i / OUT, o = i % OUT;
                sW[i] = (o < WCOLS) ? w[(kc + k) * WCOLS + o] : 0.0f;
            }
        }
        for (int i = tid * 4; i < 64 * KC; i += 1024) {
            int r = i / KC, c = i % KC;
            int gn = base + r;
            float4 v = make_float4(0.f, 0.f, 0.f, 0.f);
            if (gn < NN)
                v = *reinterpret_cast<const float4*>(&h[(size_t)gn * hstride + kc + c]);
            if (RELU_IN) {
                v.x = fmaxf(v.x, 0.f); v.y = fmaxf(v.y, 0.f);
                v.z = fmaxf(v.z, 0.f); v.w = fmaxf(v.w, 0.f);
            }
            *reinterpret_cast<float4*>(&sX[r][c]) = v;
        }
        __syncthreads();
        #pragma unroll 4
        for (int k = 0; k < KC; ++k) {
            float4 wv = *reinterpret_cast<const float4*>(&sW[k * OUT + tx * 4]);
            #pragma unroll
            for (int i = 0; i < TM; ++i) {
                float xv = sX[r0 + i][k];
                acc[i][0] = fmaf(xv, wv.x, acc[i][0]);
                acc[i][1] = fmaf(xv, wv.y, acc[i][1]);
                acc[i][2] = fmaf(xv, wv.z, acc[i][2]);
                acc[i][3] = fmaf(xv, wv.w, acc[i][3]);
            }
        }
    }

    #pragma unroll
    for (int i = 0; i < TM; ++i) {
        int gn = base + r0 + i;
        if (gn >= NN) continue;
        float4 v;
        v.x = acc[i][0]; v.y = acc[i][1]; v.z = acc[i][2]; v.w = acc[i][3];
        if (RELU_OUT) {
            v.x = fmaxf(v.x, 0.f); v.y = fmaxf(v.y, 0.f);
            v.z = fmaxf(v.z, 0.f); v.w = fmaxf(v.w, 0.f);
        }
        *reinterpret_cast<float4*>(&out[(size_t)gn * ostride + tx * 4]) = v;
    }
}

// ---------------- CSR gather, 128 channels: one wave per node ----------------
__global__ __launch_bounds__(256) void gcn_gather128_kernel(
    const int* __restrict__ csr_src, const int* __restrict__ ptr, const int* __restrict__ cnt,
    const float* __restrict__ dinv, const float* __restrict__ hw, const float* __restrict__ b,
    float* __restrict__ out)
{
    int tid = threadIdx.x;
    int n = blockIdx.x * 4 + (tid >> 6);
    if (n >= NN) return;
    int lane = tid & 63;
    float di = dinv[n];
    float2 h0 = *reinterpret_cast<const float2*>(hw + (size_t)n * 128 + lane * 2);
    float2 bb = *reinterpret_cast<const float2*>(b + lane * 2);
    float ax = bb.x + h0.x * di * di;
    float ay = bb.y + h0.y * di * di;
    int s0 = ptr[n], c = cnt[n];
    int i = 0;
    for (; i + 1 < c; i += 2) {
        int sa = csr_src[s0 + i];
        int sb = csr_src[s0 + i + 1];
        float na = dinv[sa] * di;
        float nb = dinv[sb] * di;
        float2 va = *reinterpret_cast<const float2*>(hw + (size_t)sa * 128 + lane * 2);
        float2 vb = *reinterpret_cast<const float2*>(hw + (size_t)sb * 128 + lane * 2);
        ax += va.x * na + vb.x * nb;
        ay += va.y * na + vb.y * nb;
    }
    if (i < c) {
        int sa = csr_src[s0 + i];
        float na = dinv[sa] * di;
        float2 va = *reinterpret_cast<const float2*>(hw + (size_t)sa * 128 + lane * 2);
        ax += va.x * na;
        ay += va.y * na;
    }
    float2 r; r.x = ax; r.y = ay;
    *reinterpret_cast<float2*>(out + (size_t)n * 128 + lane * 2) = r;
}

// ---------------- CSR gather, 10 channels (stride 16): 16 threads per node ----------------
__global__ __launch_bounds__(256) void gcn_gather10_kernel(
    const int* __restrict__ csr_src, const int* __restrict__ ptr, const int* __restrict__ cnt,
    const float* __restrict__ dinv, const float* __restrict__ hw, const float* __restrict__ b,
    float* __restrict__ out)
{
    int idx = blockIdx.x * 256 + threadIdx.x;
    int n = idx >> 4;
    int ch = idx & 15;
    if (n >= NN || ch >= 10) return;
    float di = dinv[n];
    float acc = b[ch] + hw[n * 16 + ch] * di * di;
    int s0 = ptr[n], c = cnt[n];
    for (int i = 0; i < c; ++i) {
        int s = csr_src[s0 + i];
        acc += hw[s * 16 + ch] * (dinv[s] * di);
    }
    out[n * 16 + ch] = acc;
}

// ---------------- pooling ----------------
__global__ void zero_pool_kernel(float* __restrict__ pooled, float* __restrict__ pcnt) {
    int i = blockIdx.x * 256 + threadIdx.x;
    if (i < NG * CC) pooled[i] = 0.0f;
    if (i < NG) pcnt[i] = 0.0f;
}

__global__ void pool_kernel(const float* __restrict__ h3, const int* __restrict__ batch,
                            float* __restrict__ pooled, float* __restrict__ pcnt)
{
    int n = blockIdx.x * 256 + threadIdx.x;
    if (n >= NN) return;
    int g = batch[n];
    #pragma unroll
    for (int c = 0; c < 10; ++c) atomicAdd(&pooled[g * 10 + c], h3[n * 16 + c]);
    atomicAdd(&pcnt[g], 1.0f);
}

__global__ void pool_finish_kernel(const float* __restrict__ pooled, const float* __restrict__ pcnt,
                                   float* __restrict__ out)
{
    int g = blockIdx.x * 64 + threadIdx.x;
    if (g >= NG) return;
    float c = fmaxf(pcnt[g], 1.0f);
    float v[10];
    float m = -1e30f;
    #pragma unroll
    for (int i = 0; i < 10; ++i) { v[i] = pooled[g * 10 + i] / c; m = fmaxf(m, v[i]); }
    float s = 0.0f;
    #pragma unroll
    for (int i = 0; i < 10; ++i) s += expf(v[i] - m);
    float lse = m + logf(s);
    #pragma unroll
    for (int i = 0; i < 10; ++i) out[g * 10 + i] = v[i] - lse;
}

extern "C" void kernel_launch(void* const* d_in, const int* in_sizes, int n_in,
                              void* d_out, int out_size, void* d_ws, size_t ws_size,
                              hipStream_t stream)
{
    const float* x      = (const float*)d_in[0];
    const int*   ei     = (const int*)d_in[1];
    const int*   batch  = (const int*)d_in[2];
    const float* emb_w1 = (const float*)d_in[3];
    const float* emb_b1 = (const float*)d_in[4];
    const float* emb_w2 = (const float*)d_in[5];
    const float* emb_b2 = (const float*)d_in[6];
    const float* w1     = (const float*)d_in[7];
    const float* b1     = (const float*)d_in[8];
    const float* w2     = (const float*)d_in[9];
    const float* b2     = (const float*)d_in[10];
    const float* w3     = (const float*)d_in[11];
    const float* b3     = (const float*)d_in[12];

    int E = in_sizes[1] / 2;
    const int* src = ei;
    const int* dst = ei + E;

    // workspace layout
    char* ws = (char*)d_ws;
    size_t off = 0;
    float* bufA   = (float*)(ws + off); off += (size_t)NN * 128 * 4;
    float* bufB   = (float*)(ws + off); off += (size_t)NN * 128 * 4;
    float* dinv   = (float*)(ws + off); off += (size_t)NN * 4;
    int*   cnt    = (int*)(ws + off);   off += (size_t)NN * 4;
    int*   ptr    = (int*)(ws + off);   off += (size_t)NN * 4;
    int*   fill   = (int*)(ws + off);   off += (size_t)NN * 4;
    int*   bsum   = (int*)(ws + off);   off += 256 * 4;
    int*   csrs   = (int*)(ws + off);   off += (size_t)E * 4;
    float* pooled = (float*)(ws + off); off += (size_t)NG * CC * 4;
    float* pcnt   = (float*)(ws + off); off += (size_t)NG * 4;

    int mmgrid = cdiv(NN, 64);

    // ---- CSR build ----
    zero_int_kernel<<<cdiv(NN, 256), 256, 0, stream>>>(cnt, fill);
    count_kernel<<<cdiv(E, 256), 256, 0, stream>>>(dst, cnt, E);
    dinv_kernel<<<cdiv(NN, 256), 256, 0, stream>>>(cnt, dinv);
    scan_block_kernel<<<NBS, 256, 0, stream>>>(cnt, ptr, bsum);
    scan_tops_kernel<<<1, 256, 0, stream>>>(bsum);
    scan_add_kernel<<<NBS, 256, 0, stream>>>(ptr, bsum);
    csr_fill_kernel<<<cdiv(E, 256), 256, 0, stream>>>(src, dst, ptr, fill, csrs, E);

    // ---- embedder: x -> bufB -> bufA (both [NN,64]) ----
    mm_kernel<64, 64, 64, false, true, true><<<mmgrid, 256, 0, stream>>>(x, 64, emb_w1, emb_b1, bufB, 64);
    mm_kernel<64, 64, 64, false, true, true><<<mmgrid, 256, 0, stream>>>(bufB, 64, emb_w2, emb_b2, bufA, 64);

    // ---- GCN layer 1: 64 -> 128 ----
    mm_kernel<64, 128, 128, false, false, false><<<mmgrid, 256, 0, stream>>>(bufA, 64, w1, nullptr, bufB, 128);
    gcn_gather128_kernel<<<cdiv(NN, 4), 256, 0, stream>>>(csrs, ptr, cnt, dinv, bufB, b1, bufA);

    // ---- GCN layer 2: 128 -> 128 (relu fused into X load) ----
    mm_kernel<128, 128, 128, true, false, false><<<mmgrid, 256, 0, stream>>>(bufA, 128, w2, nullptr, bufB, 128);
    gcn_gather128_kernel<<<cdiv(NN, 4), 256, 0, stream>>>(csrs, ptr, cnt, dinv, bufB, b2, bufA);

    // ---- GCN layer 3: 128 -> 10 (W padded to 16 cols; rows stride 16) ----
    mm_kernel<128, 16, 10, true, false, false><<<mmgrid, 256, 0, stream>>>(bufA, 128, w3, nullptr, bufB, 16);
    gcn_gather10_kernel<<<cdiv(NN * 16, 256), 256, 0, stream>>>(csrs, ptr, cnt, dinv, bufB, b3, bufA);

    // ---- pooling + log_softmax ----
    zero_pool_kernel<<<cdiv(NG * CC, 256), 256, 0, stream>>>(pooled, pcnt);
    pool_kernel<<<cdiv(NN, 256), 256, 0, stream>>>(bufA, batch, pooled, pcnt);
    pool_finish_kernel<<<cdiv(NG, 64), 64, 0, stream>>>(pooled, pcnt, (float*)d_out);
}

// Round 4
// 340.945 us; speedup vs baseline: 10.1745x; 1.1861x over previous
//
#include <hip/hip_runtime.h>
#include <math.h>

#define NN 50000      // nodes
#define NG 500        // graphs
#define CC 10
#define NBS 196       // cdiv(NN,256) scan blocks

static inline int cdiv(int a, int b) { return (a + b - 1) / b; }

// ---------------- CSR build ----------------
__global__ void zero_int_kernel(int* __restrict__ a, int* __restrict__ b) {
    int i = blockIdx.x * 256 + threadIdx.x;
    if (i < NN) { a[i] = 0; b[i] = 0; }
}

__global__ void count_kernel(const int* __restrict__ dst, int* __restrict__ cnt, int nedges) {
    int e = blockIdx.x * 256 + threadIdx.x;
    if (e < nedges) atomicAdd(&cnt[dst[e]], 1);
}

__global__ void dinv_kernel(const int* __restrict__ cnt, float* __restrict__ dinv) {
    int n = blockIdx.x * 256 + threadIdx.x;
    if (n < NN) dinv[n] = rsqrtf((float)cnt[n] + 1.0f);  // +1 self-loop
}

__global__ void scan_block_kernel(const int* __restrict__ cnt, int* __restrict__ ptr, int* __restrict__ bsum) {
    __shared__ int s[256];
    int b = blockIdx.x, t = threadIdx.x;
    int i = b * 256 + t;
    int v = (i < NN) ? cnt[i] : 0;
    s[t] = v; __syncthreads();
    for (int off = 1; off < 256; off <<= 1) {
        int x = (t >= off) ? s[t - off] : 0; __syncthreads();
        s[t] += x; __syncthreads();
    }
    if (i < NN) ptr[i] = s[t] - v;
    if (t == 255) bsum[b] = s[255];
}

__global__ void scan_tops_kernel(int* __restrict__ bsum) {
    __shared__ int s[256];
    int t = threadIdx.x;
    int v = (t < NBS) ? bsum[t] : 0;
    s[t] = v; __syncthreads();
    for (int off = 1; off < 256; off <<= 1) {
        int x = (t >= off) ? s[t - off] : 0; __syncthreads();
        s[t] += x; __syncthreads();
    }
    if (t < NBS) bsum[t] = s[t] - v;
}

__global__ void scan_add_kernel(int* __restrict__ ptr, const int* __restrict__ bsum) {
    int i = blockIdx.x * 256 + threadIdx.x;
    if (i < NN) ptr[i] += bsum[blockIdx.x];
}

__global__ void csr_fill_kernel(const int* __restrict__ src, const int* __restrict__ dst,
                                const int* __restrict__ ptr, int* __restrict__ fill,
                                int* __restrict__ csr_src, int nedges) {
    int e = blockIdx.x * 256 + threadIdx.x;
    if (e >= nedges) return;
    int d = dst[e];
    int pos = ptr[d] + atomicAdd(&fill[d], 1);
    csr_src[pos] = src[e];
}

// ---------------- register-tiled dense matmul: out = (relu?)(h) @ W [+bias] ----------------
template <int K, int OUT, int WCOLS, bool RELU_IN, bool RELU_OUT, bool BIAS>
__global__ __launch_bounds__(256) void mm_kernel(
    const float* __restrict__ h, int hstride,
    const float* __restrict__ w, const float* __restrict__ bias,
    float* __restrict__ out, int ostride)
{
    constexpr int KC = 64;
    constexpr int NCH = K / KC;
    constexpr int NCOL = OUT / 4;
    constexpr int NROW = 256 / NCOL;
    constexpr int TM = 64 / NROW;
    __shared__ float sW[KC * OUT];
    __shared__ float sX[64][KC + 4];
    int tid = threadIdx.x;
    int tx = tid % NCOL, ty = tid / NCOL;
    int base = blockIdx.x * 64;
    int r0 = ty * TM;

    float acc[TM][4];
    #pragma unroll
    for (int i = 0; i < TM; ++i) {
        #pragma unroll
        for (int j = 0; j < 4; ++j)
            acc[i][j] = BIAS ? ((tx * 4 + j < WCOLS) ? bias[tx * 4 + j] : 0.0f) : 0.0f;
    }

    for (int ch = 0; ch < NCH; ++ch) {
        int kc = ch * KC;
        if (ch) __syncthreads();
        if constexpr (WCOLS == OUT) {
            for (int i = tid * 4; i < KC * OUT; i += 1024)
                *reinterpret_cast<float4*>(&sW[i]) =
                    *reinterpret_cast<const float4*>(&w[kc * OUT + i]);
        } else {
            for (int i = tid; i < KC * OUT; i += 256) {
                int k = i / OUT, o = i % OUT;
                sW[i] = (o < WCOLS) ? w[(kc + k) * WCOLS + o] : 0.0f;
            }
        }
        for (int i = tid * 4; i < 64 * KC; i += 1024) {
            int r = i / KC, c = i % KC;
            int gn = base + r;
            float4 v = make_float4(0.f, 0.f, 0.f, 0.f);
            if (gn < NN)
                v = *reinterpret_cast<const float4*>(&h[(size_t)gn * hstride + kc + c]);
            if (RELU_IN) {
                v.x = fmaxf(v.x, 0.f); v.y = fmaxf(v.y, 0.f);
                v.z = fmaxf(v.z, 0.f); v.w = fmaxf(v.w, 0.f);
            }
            *reinterpret_cast<float4*>(&sX[r][c]) = v;
        }
        __syncthreads();
        #pragma unroll 4
        for (int k = 0; k < KC; ++k) {
            float4 wv = *reinterpret_cast<const float4*>(&sW[k * OUT + tx * 4]);
            #pragma unroll
            for (int i = 0; i < TM; ++i) {
                float xv = sX[r0 + i][k];
                acc[i][0] = fmaf(xv, wv.x, acc[i][0]);
                acc[i][1] = fmaf(xv, wv.y, acc[i][1]);
                acc[i][2] = fmaf(xv, wv.z, acc[i][2]);
                acc[i][3] = fmaf(xv, wv.w, acc[i][3]);
            }
        }
    }

    #pragma unroll
    for (int i = 0; i < TM; ++i) {
        int gn = base + r0 + i;
        if (gn >= NN) continue;
        float4 v;
        v.x = acc[i][0]; v.y = acc[i][1]; v.z = acc[i][2]; v.w = acc[i][3];
        if (RELU_OUT) {
            v.x = fmaxf(v.x, 0.f); v.y = fmaxf(v.y, 0.f);
            v.z = fmaxf(v.z, 0.f); v.w = fmaxf(v.w, 0.f);
        }
        *reinterpret_cast<float4*>(&out[(size_t)gn * ostride + tx * 4]) = v;
    }
}

// ---------------- CSR gather, 128 channels: one wave per node ----------------
__global__ __launch_bounds__(256) void gcn_gather128_kernel(
    const int* __restrict__ csr_src, const int* __restrict__ ptr, const int* __restrict__ cnt,
    const float* __restrict__ dinv, const float* __restrict__ hw, const float* __restrict__ b,
    float* __restrict__ out)
{
    int tid = threadIdx.x;
    int n = blockIdx.x * 4 + (tid >> 6);
    if (n >= NN) return;
    int lane = tid & 63;
    float di = dinv[n];
    float2 h0 = *reinterpret_cast<const float2*>(hw + (size_t)n * 128 + lane * 2);
    float2 bb = *reinterpret_cast<const float2*>(b + lane * 2);
    float ax = bb.x + h0.x * di * di;
    float ay = bb.y + h0.y * di * di;
    int s0 = ptr[n], c = cnt[n];
    int i = 0;
    for (; i + 1 < c; i += 2) {
        int sa = csr_src[s0 + i];
        int sb = csr_src[s0 + i + 1];
        float na = dinv[sa] * di;
        float nb = dinv[sb] * di;
        float2 va = *reinterpret_cast<const float2*>(hw + (size_t)sa * 128 + lane * 2);
        float2 vb = *reinterpret_cast<const float2*>(hw + (size_t)sb * 128 + lane * 2);
        ax += va.x * na + vb.x * nb;
        ay += va.y * na + vb.y * nb;
    }
    if (i < c) {
        int sa = csr_src[s0 + i];
        float na = dinv[sa] * di;
        float2 va = *reinterpret_cast<const float2*>(hw + (size_t)sa * 128 + lane * 2);
        ax += va.x * na;
        ay += va.y * na;
    }
    float2 r; r.x = ax; r.y = ay;
    *reinterpret_cast<float2*>(out + (size_t)n * 128 + lane * 2) = r;
}

// ---------------- CSR gather, 10 channels (stride 16): 16 threads per node ----------------
__global__ __launch_bounds__(256) void gcn_gather10_kernel(
    const int* __restrict__ csr_src, const int* __restrict__ ptr, const int* __restrict__ cnt,
    const float* __restrict__ dinv, const float* __restrict__ hw, const float* __restrict__ b,
    float* __restrict__ out)
{
    int idx = blockIdx.x * 256 + threadIdx.x;
    int n = idx >> 4;
    int ch = idx & 15;
    if (n >= NN || ch >= 10) return;
    float di = dinv[n];
    float acc = b[ch] + hw[n * 16 + ch] * di * di;
    int s0 = ptr[n], c = cnt[n];
    for (int i = 0; i < c; ++i) {
        int s = csr_src[s0 + i];
        acc += hw[s * 16 + ch] * (dinv[s] * di);
    }
    out[n * 16 + ch] = acc;
}

// ---------------- fused segmented pool + log_softmax (batch is sorted) ----------------
__global__ __launch_bounds__(256) void pool_ls_kernel(
    const float* __restrict__ h3, const int* __restrict__ batch, float* __restrict__ out)
{
    __shared__ int seg[2];
    __shared__ float red[16][17];
    int g = blockIdx.x;
    int t = threadIdx.x;
    if (t < 2) {
        int target = g + t;
        int lo = 0, hi = NN;
        while (lo < hi) {            // lower_bound: first i with batch[i] >= target
            int mid = (lo + hi) >> 1;
            if (batch[mid] < target) lo = mid + 1; else hi = mid;
        }
        seg[t] = lo;
    }
    __syncthreads();
    int s = seg[0], e = seg[1];
    int ch = t & 15, nl = t >> 4;
    float acc = 0.0f;
    for (int n = s + nl; n < e; n += 16)
        if (ch < 10) acc += h3[(size_t)n * 16 + ch];
    red[nl][ch] = acc;
    __syncthreads();
    if (t < 16) {
        float ssum = 0.0f;
        #pragma unroll
        for (int i = 0; i < 16; ++i) ssum += red[i][t];
        red[0][t] = ssum;
    }
    __syncthreads();
    if (t == 0) {
        float c = fmaxf((float)(e - s), 1.0f);
        float v[10], m = -1e30f;
        #pragma unroll
        for (int i = 0; i < 10; ++i) { v[i] = red[0][i] / c; m = fmaxf(m, v[i]); }
        float ssum = 0.0f;
        #pragma unroll
        for (int i = 0; i < 10; ++i) ssum += expf(v[i] - m);
        float lse = m + logf(ssum);
        #pragma unroll
        for (int i = 0; i < 10; ++i) out[g * 10 + i] = v[i] - lse;
    }
}

extern "C" void kernel_launch(void* const* d_in, const int* in_sizes, int n_in,
                              void* d_out, int out_size, void* d_ws, size_t ws_size,
                              hipStream_t stream)
{
    const float* x      = (const float*)d_in[0];
    const int*   ei     = (const int*)d_in[1];
    const int*   batch  = (const int*)d_in[2];
    const float* emb_w1 = (const float*)d_in[3];
    const float* emb_b1 = (const float*)d_in[4];
    const float* emb_w2 = (const float*)d_in[5];
    const float* emb_b2 = (const float*)d_in[6];
    const float* w1     = (const float*)d_in[7];
    const float* b1     = (const float*)d_in[8];
    const float* w2     = (const float*)d_in[9];
    const float* b2     = (const float*)d_in[10];
    const float* w3     = (const float*)d_in[11];
    const float* b3     = (const float*)d_in[12];

    int E = in_sizes[1] / 2;
    const int* src = ei;
    const int* dst = ei + E;

    // workspace layout
    char* ws = (char*)d_ws;
    size_t off = 0;
    float* bufA   = (float*)(ws + off); off += (size_t)NN * 128 * 4;
    float* bufB   = (float*)(ws + off); off += (size_t)NN * 128 * 4;
    float* dinv   = (float*)(ws + off); off += (size_t)NN * 4;
    int*   cnt    = (int*)(ws + off);   off += (size_t)NN * 4;
    int*   ptr    = (int*)(ws + off);   off += (size_t)NN * 4;
    int*   fill   = (int*)(ws + off);   off += (size_t)NN * 4;
    int*   bsum   = (int*)(ws + off);   off += 256 * 4;
    int*   csrs   = (int*)(ws + off);   off += (size_t)E * 4;

    int mmgrid = cdiv(NN, 64);

    // ---- CSR build ----
    zero_int_kernel<<<cdiv(NN, 256), 256, 0, stream>>>(cnt, fill);
    count_kernel<<<cdiv(E, 256), 256, 0, stream>>>(dst, cnt, E);
    dinv_kernel<<<cdiv(NN, 256), 256, 0, stream>>>(cnt, dinv);
    scan_block_kernel<<<NBS, 256, 0, stream>>>(cnt, ptr, bsum);
    scan_tops_kernel<<<1, 256, 0, stream>>>(bsum);
    scan_add_kernel<<<NBS, 256, 0, stream>>>(ptr, bsum);
    csr_fill_kernel<<<cdiv(E, 256), 256, 0, stream>>>(src, dst, ptr, fill, csrs, E);

    // ---- embedder: x -> bufB -> bufA (both [NN,64]) ----
    mm_kernel<64, 64, 64, false, true, true><<<mmgrid, 256, 0, stream>>>(x, 64, emb_w1, emb_b1, bufB, 64);
    mm_kernel<64, 64, 64, false, true, true><<<mmgrid, 256, 0, stream>>>(bufB, 64, emb_w2, emb_b2, bufA, 64);

    // ---- GCN layer 1: 64 -> 128 ----
    mm_kernel<64, 128, 128, false, false, false><<<mmgrid, 256, 0, stream>>>(bufA, 64, w1, nullptr, bufB, 128);
    gcn_gather128_kernel<<<cdiv(NN, 4), 256, 0, stream>>>(csrs, ptr, cnt, dinv, bufB, b1, bufA);

    // ---- GCN layer 2: 128 -> 128 (relu fused into X load) ----
    mm_kernel<128, 128, 128, true, false, false><<<mmgrid, 256, 0, stream>>>(bufA, 128, w2, nullptr, bufB, 128);
    gcn_gather128_kernel<<<cdiv(NN, 4), 256, 0, stream>>>(csrs, ptr, cnt, dinv, bufB, b2, bufA);

    // ---- GCN layer 3: 128 -> 10 (W padded to 16 cols; rows stride 16) ----
    mm_kernel<128, 16, 10, true, false, false><<<mmgrid, 256, 0, stream>>>(bufA, 128, w3, nullptr, bufB, 16);
    gcn_gather10_kernel<<<cdiv(NN * 16, 256), 256, 0, stream>>>(csrs, ptr, cnt, dinv, bufB, b3, bufA);

    // ---- fused pooling + log_softmax (one block per graph) ----
    pool_ls_kernel<<<NG, 256, 0, stream>>>(bufA, batch, (float*)d_out);
}

// Round 5
// 297.199 us; speedup vs baseline: 11.6721x; 1.1472x over previous
//
#include <hip/hip_runtime.h>
#include <math.h>

#define NN 50000      // nodes
#define NG 500        // graphs
#define CC 10
#define NBS 196       // cdiv(NN,256) scan blocks

static inline int cdiv(int a, int b) { return (a + b - 1) / b; }

__device__ inline unsigned bf16rne(float f) {
    unsigned u = __float_as_uint(f);
    return (u + 0x7fffu + ((u >> 16) & 1u)) >> 16;
}
__device__ inline unsigned pack2bf(float a, float b) {
    return bf16rne(a) | (bf16rne(b) << 16);
}

// ---------------- CSR build ----------------
__global__ void zero_int_kernel(int* __restrict__ a, int* __restrict__ b) {
    int i = blockIdx.x * 256 + threadIdx.x;
    if (i < NN) { a[i] = 0; b[i] = 0; }
}

__global__ void count_kernel(const int* __restrict__ dst, int* __restrict__ cnt, int nedges) {
    int e = blockIdx.x * 256 + threadIdx.x;
    if (e < nedges) atomicAdd(&cnt[dst[e]], 1);
}

__global__ void dinv_kernel(const int* __restrict__ cnt, float* __restrict__ dinv) {
    int n = blockIdx.x * 256 + threadIdx.x;
    if (n < NN) dinv[n] = rsqrtf((float)cnt[n] + 1.0f);  // +1 self-loop
}

__global__ void scan_block_kernel(const int* __restrict__ cnt, int* __restrict__ ptr, int* __restrict__ bsum) {
    __shared__ int s[256];
    int b = blockIdx.x, t = threadIdx.x;
    int i = b * 256 + t;
    int v = (i < NN) ? cnt[i] : 0;
    s[t] = v; __syncthreads();
    for (int off = 1; off < 256; off <<= 1) {
        int x = (t >= off) ? s[t - off] : 0; __syncthreads();
        s[t] += x; __syncthreads();
    }
    if (i < NN) ptr[i] = s[t] - v;
    if (t == 255) bsum[b] = s[255];
}

__global__ void scan_tops_kernel(int* __restrict__ bsum) {
    __shared__ int s[256];
    int t = threadIdx.x;
    int v = (t < NBS) ? bsum[t] : 0;
    s[t] = v; __syncthreads();
    for (int off = 1; off < 256; off <<= 1) {
        int x = (t >= off) ? s[t - off] : 0; __syncthreads();
        s[t] += x; __syncthreads();
    }
    if (t < NBS) bsum[t] = s[t] - v;
}

__global__ void scan_add_kernel(int* __restrict__ ptr, const int* __restrict__ bsum) {
    int i = blockIdx.x * 256 + threadIdx.x;
    if (i < NN) ptr[i] += bsum[blockIdx.x];
}

__global__ void csr_fill_kernel(const int* __restrict__ src, const int* __restrict__ dst,
                                const int* __restrict__ ptr, int* __restrict__ fill,
                                int* __restrict__ csr_src, int nedges) {
    int e = blockIdx.x * 256 + threadIdx.x;
    if (e >= nedges) return;
    int d = dst[e];
    int pos = ptr[d] + atomicAdd(&fill[d], 1);
    csr_src[pos] = src[e];
}

// ---------------- register-tiled dense matmul: out = (relu?)(h) @ W [+bias] ----------------
// OUT_BF16: write packed 2xbf16 dwords instead of fp32 (ostride in fp32 elements).
template <int K, int OUT, int WCOLS, bool RELU_IN, bool RELU_OUT, bool BIAS, bool OUT_BF16>
__global__ __launch_bounds__(256) void mm_kernel(
    const float* __restrict__ h, int hstride,
    const float* __restrict__ w, const float* __restrict__ bias,
    float* __restrict__ out, int ostride)
{
    constexpr int KC = 64;
    constexpr int NCH = K / KC;
    constexpr int NCOL = OUT / 4;
    constexpr int NROW = 256 / NCOL;
    constexpr int TM = 64 / NROW;
    __shared__ float sW[KC * OUT];
    __shared__ float sX[64][KC + 4];
    int tid = threadIdx.x;
    int tx = tid % NCOL, ty = tid / NCOL;
    int base = blockIdx.x * 64;
    int r0 = ty * TM;

    float acc[TM][4];
    #pragma unroll
    for (int i = 0; i < TM; ++i) {
        #pragma unroll
        for (int j = 0; j < 4; ++j)
            acc[i][j] = BIAS ? ((tx * 4 + j < WCOLS) ? bias[tx * 4 + j] : 0.0f) : 0.0f;
    }

    for (int ch = 0; ch < NCH; ++ch) {
        int kc = ch * KC;
        if (ch) __syncthreads();
        if constexpr (WCOLS == OUT) {
            for (int i = tid * 4; i < KC * OUT; i += 1024)
                *reinterpret_cast<float4*>(&sW[i]) =
                    *reinterpret_cast<const float4*>(&w[kc * OUT + i]);
        } else {
            for (int i = tid; i < KC * OUT; i += 256) {
                int k = i / OUT, o = i % OUT;
                sW[i] = (o < WCOLS) ? w[(kc + k) * WCOLS + o] : 0.0f;
            }
        }
        for (int i = tid * 4; i < 64 * KC; i += 1024) {
            int r = i / KC, c = i % KC;
            int gn = base + r;
            float4 v = make_float4(0.f, 0.f, 0.f, 0.f);
            if (gn < NN)
                v = *reinterpret_cast<const float4*>(&h[(size_t)gn * hstride + kc + c]);
            if (RELU_IN) {
                v.x = fmaxf(v.x, 0.f); v.y = fmaxf(v.y, 0.f);
                v.z = fmaxf(v.z, 0.f); v.w = fmaxf(v.w, 0.f);
            }
            *reinterpret_cast<float4*>(&sX[r][c]) = v;
        }
        __syncthreads();
        #pragma unroll 4
        for (int k = 0; k < KC; ++k) {
            float4 wv = *reinterpret_cast<const float4*>(&sW[k * OUT + tx * 4]);
            #pragma unroll
            for (int i = 0; i < TM; ++i) {
                float xv = sX[r0 + i][k];
                acc[i][0] = fmaf(xv, wv.x, acc[i][0]);
                acc[i][1] = fmaf(xv, wv.y, acc[i][1]);
                acc[i][2] = fmaf(xv, wv.z, acc[i][2]);
                acc[i][3] = fmaf(xv, wv.w, acc[i][3]);
            }
        }
    }

    #pragma unroll
    for (int i = 0; i < TM; ++i) {
        int gn = base + r0 + i;
        if (gn >= NN) continue;
        float4 v;
        v.x = acc[i][0]; v.y = acc[i][1]; v.z = acc[i][2]; v.w = acc[i][3];
        if (RELU_OUT) {
            v.x = fmaxf(v.x, 0.f); v.y = fmaxf(v.y, 0.f);
            v.z = fmaxf(v.z, 0.f); v.w = fmaxf(v.w, 0.f);
        }
        if constexpr (OUT_BF16) {
            unsigned* orow = reinterpret_cast<unsigned*>(out) + (size_t)gn * (ostride >> 1) + tx * 2;
            uint2 pv;
            pv.x = pack2bf(v.x, v.y);
            pv.y = pack2bf(v.z, v.w);
            *reinterpret_cast<uint2*>(orow) = pv;
        } else {
            *reinterpret_cast<float4*>(&out[(size_t)gn * ostride + tx * 4]) = v;
        }
    }
}

// ---------------- CSR gather, 128 bf16 channels: one wave per node ----------------
// hw rows: 64 dwords, each = 2 packed bf16. Lane handles channels 2*lane, 2*lane+1.
__global__ __launch_bounds__(256) void gcn_gather128_bf16_kernel(
    const int* __restrict__ csr_src, const int* __restrict__ ptr, const int* __restrict__ cnt,
    const float* __restrict__ dinv, const unsigned* __restrict__ hw, const float* __restrict__ b,
    float* __restrict__ out)
{
    int tid = threadIdx.x;
    int n = blockIdx.x * 4 + (tid >> 6);
    if (n >= NN) return;
    int lane = tid & 63;
    float di = dinv[n];
    unsigned p0 = hw[(size_t)n * 64 + lane];
    float2 bb = *reinterpret_cast<const float2*>(b + lane * 2);
    float ax = bb.x + __uint_as_float(p0 << 16) * di * di;
    float ay = bb.y + __uint_as_float(p0 & 0xffff0000u) * di * di;
    int s0 = ptr[n], c = cnt[n];
    int i = 0;
    for (; i + 3 < c; i += 4) {
        int sa = csr_src[s0 + i + 0];
        int sb = csr_src[s0 + i + 1];
        int sc = csr_src[s0 + i + 2];
        int sd = csr_src[s0 + i + 3];
        float na = dinv[sa] * di, nb = dinv[sb] * di;
        float nc = dinv[sc] * di, nd = dinv[sd] * di;
        unsigned pa = hw[(size_t)sa * 64 + lane];
        unsigned pb = hw[(size_t)sb * 64 + lane];
        unsigned pc = hw[(size_t)sc * 64 + lane];
        unsigned pd = hw[(size_t)sd * 64 + lane];
        ax = fmaf(__uint_as_float(pa << 16), na, ax);
        ay = fmaf(__uint_as_float(pa & 0xffff0000u), na, ay);
        ax = fmaf(__uint_as_float(pb << 16), nb, ax);
        ay = fmaf(__uint_as_float(pb & 0xffff0000u), nb, ay);
        ax = fmaf(__uint_as_float(pc << 16), nc, ax);
        ay = fmaf(__uint_as_float(pc & 0xffff0000u), nc, ay);
        ax = fmaf(__uint_as_float(pd << 16), nd, ax);
        ay = fmaf(__uint_as_float(pd & 0xffff0000u), nd, ay);
    }
    for (; i < c; ++i) {
        int sa = csr_src[s0 + i];
        float na = dinv[sa] * di;
        unsigned pa = hw[(size_t)sa * 64 + lane];
        ax = fmaf(__uint_as_float(pa << 16), na, ax);
        ay = fmaf(__uint_as_float(pa & 0xffff0000u), na, ay);
    }
    float2 r; r.x = ax; r.y = ay;
    *reinterpret_cast<float2*>(out + (size_t)n * 128 + lane * 2) = r;
}

// ---------------- CSR gather, 10 channels (stride 16): 16 threads per node ----------------
__global__ void gcn_gather10_kernel(
    const int* __restrict__ csr_src, const int* __restrict__ ptr, const int* __restrict__ cnt,
    const float* __restrict__ dinv, const float* __restrict__ hw, const float* __restrict__ b,
    float* __restrict__ out)
{
    int idx = blockIdx.x * 256 + threadIdx.x;
    int n = idx >> 4;
    int ch = idx & 15;
    if (n >= NN || ch >= 10) return;
    float di = dinv[n];
    float acc = b[ch] + hw[n * 16 + ch] * di * di;
    int s0 = ptr[n], c = cnt[n];
    for (int i = 0; i < c; ++i) {
        int s = csr_src[s0 + i];
        acc += hw[s * 16 + ch] * (dinv[s] * di);
    }
    out[n * 16 + ch] = acc;
}

// ---------------- fused segmented pool + log_softmax (batch is sorted) ----------------
__global__ __launch_bounds__(256) void pool_ls_kernel(
    const float* __restrict__ h3, const int* __restrict__ batch, float* __restrict__ out)
{
    __shared__ int seg[2];
    __shared__ float red[16][17];
    int g = blockIdx.x;
    int t = threadIdx.x;
    if (t < 2) {
        int target = g + t;
        int lo = 0, hi = NN;
        while (lo < hi) {
            int mid = (lo + hi) >> 1;
            if (batch[mid] < target) lo = mid + 1; else hi = mid;
        }
        seg[t] = lo;
    }
    __syncthreads();
    int s = seg[0], e = seg[1];
    int ch = t & 15, nl = t >> 4;
    float acc = 0.0f;
    for (int n = s + nl; n < e; n += 16)
        if (ch < 10) acc += h3[(size_t)n * 16 + ch];
    red[nl][ch] = acc;
    __syncthreads();
    if (t < 16) {
        float ssum = 0.0f;
        #pragma unroll
        for (int i = 0; i < 16; ++i) ssum += red[i][t];
        red[0][t] = ssum;
    }
    __syncthreads();
    if (t == 0) {
        float c = fmaxf((float)(e - s), 1.0f);
        float v[10], m = -1e30f;
        #pragma unroll
        for (int i = 0; i < 10; ++i) { v[i] = red[0][i] / c; m = fmaxf(m, v[i]); }
        float ssum = 0.0f;
        #pragma unroll
        for (int i = 0; i < 10; ++i) ssum += expf(v[i] - m);
        float lse = m + logf(ssum);
        #pragma unroll
        for (int i = 0; i < 10; ++i) out[g * 10 + i] = v[i] - lse;
    }
}

extern "C" void kernel_launch(void* const* d_in, const int* in_sizes, int n_in,
                              void* d_out, int out_size, void* d_ws, size_t ws_size,
                              hipStream_t stream)
{
    const float* x      = (const float*)d_in[0];
    const int*   ei     = (const int*)d_in[1];
    const int*   batch  = (const int*)d_in[2];
    const float* emb_w1 = (const float*)d_in[3];
    const float* emb_b1 = (const float*)d_in[4];
    const float* emb_w2 = (const float*)d_in[5];
    const float* emb_b2 = (const float*)d_in[6];
    const float* w1     = (const float*)d_in[7];
    const float* b1     = (const float*)d_in[8];
    const float* w2     = (const float*)d_in[9];
    const float* b2     = (const float*)d_in[10];
    const float* w3     = (const float*)d_in[11];
    const float* b3     = (const float*)d_in[12];

    int E = in_sizes[1] / 2;
    const int* src = ei;
    const int* dst = ei + E;

    // workspace layout
    char* ws = (char*)d_ws;
    size_t off = 0;
    float* bufA   = (float*)(ws + off); off += (size_t)NN * 128 * 4;   // fp32 [NN,128]
    float* bufB   = (float*)(ws + off); off += (size_t)NN * 128 * 4;   // fp32; first half also emb tmp / layer3 out
    float* dinv   = (float*)(ws + off); off += (size_t)NN * 4;
    int*   cnt    = (int*)(ws + off);   off += (size_t)NN * 4;
    int*   ptr    = (int*)(ws + off);   off += (size_t)NN * 4;
    int*   fill   = (int*)(ws + off);   off += (size_t)NN * 4;
    int*   bsum   = (int*)(ws + off);   off += 256 * 4;
    int*   csrs   = (int*)(ws + off);   off += (size_t)E * 4;

    // bf16 hw buffer aliased into bufB's second half (NN*64 dwords = 12.8 MB);
    // bufB's first region (emb tmp NN*64 f32, layer3 out NN*16 f32) never overlaps it in time.
    unsigned* hwb = (unsigned*)(bufB + (size_t)NN * 64);

    int mmgrid = cdiv(NN, 64);

    // ---- CSR build ----
    zero_int_kernel<<<cdiv(NN, 256), 256, 0, stream>>>(cnt, fill);
    count_kernel<<<cdiv(E, 256), 256, 0, stream>>>(dst, cnt, E);
    dinv_kernel<<<cdiv(NN, 256), 256, 0, stream>>>(cnt, dinv);
    scan_block_kernel<<<NBS, 256, 0, stream>>>(cnt, ptr, bsum);
    scan_tops_kernel<<<1, 256, 0, stream>>>(bsum);
    scan_add_kernel<<<NBS, 256, 0, stream>>>(ptr, bsum);
    csr_fill_kernel<<<cdiv(E, 256), 256, 0, stream>>>(src, dst, ptr, fill, csrs, E);

    // ---- embedder: x -> bufB(first half) -> bufA, both [NN,64] fp32 ----
    mm_kernel<64, 64, 64, false, true, true, false><<<mmgrid, 256, 0, stream>>>(x, 64, emb_w1, emb_b1, bufB, 64);
    mm_kernel<64, 64, 64, false, true, true, false><<<mmgrid, 256, 0, stream>>>(bufB, 64, emb_w2, emb_b2, bufA, 64);

    // ---- GCN layer 1: 64 -> 128, bf16 hw ----
    mm_kernel<64, 128, 128, false, false, false, true><<<mmgrid, 256, 0, stream>>>(bufA, 64, w1, nullptr, (float*)hwb, 128);
    gcn_gather128_bf16_kernel<<<cdiv(NN, 4), 256, 0, stream>>>(csrs, ptr, cnt, dinv, hwb, b1, bufA);

    // ---- GCN layer 2: 128 -> 128 (relu fused into X load), bf16 hw ----
    mm_kernel<128, 128, 128, true, false, false, true><<<mmgrid, 256, 0, stream>>>(bufA, 128, w2, nullptr, (float*)hwb, 128);
    gcn_gather128_bf16_kernel<<<cdiv(NN, 4), 256, 0, stream>>>(csrs, ptr, cnt, dinv, hwb, b2, bufA);

    // ---- GCN layer 3: 128 -> 10 fp32 (W padded to 16 cols) ----
    mm_kernel<128, 16, 10, true, false, false, false><<<mmgrid, 256, 0, stream>>>(bufA, 128, w3, nullptr, bufB, 16);
    gcn_gather10_kernel<<<cdiv(NN * 16, 256), 256, 0, stream>>>(csrs, ptr, cnt, dinv, bufB, b3, bufA);

    // ---- fused pooling + log_softmax (one block per graph) ----
    pool_ls_kernel<<<NG, 256, 0, stream>>>(bufA, batch, (float*)d_out);
}